// Round 11
// baseline (351.050 us; speedup 1.0000x reference)
//
#include <hip/hip_runtime.h>
#include <hip/hip_bf16.h>
#include <math.h>

// Problem constants (B=2, T=4096, D=2048, H=2048, W=4)
#define B_DIM 2
#define T_DIM 4096
#define D_DIM 2048
#define H_DIM 2048
#define W_K   4
#define M_DIM (B_DIM * T_DIM)   // 8192 tokens
#define N2_DIM (D_DIM * W_K)    // 8192

typedef __bf16 bf16x8 __attribute__((ext_vector_type(8)));
typedef float  f32x4  __attribute__((ext_vector_type(4)));

// 256x256 tile, K-tile 32, TRIPLE-buffered (3 x (A16K+B16K) = 96KB LDS),
// 8 waves (2M x 4N). One barrier + one counted vmcnt per K-tile; the whole
// {reads, stage-issues, MFMA} of a tile is a single barrier-free region.
#define BM 256
#define BN 256
#define BKT 32
#define XW_STRIDE 68   // f32 stride for epilogue x-window

__device__ __forceinline__ unsigned short f2bf(float f) {
    unsigned int u = __float_as_uint(f);
    unsigned int r = (u + 0x7FFFu + ((u >> 16) & 1u)) >> 16;  // RNE
    return (unsigned short)r;
}

__device__ __forceinline__ float silu_f(float v) {
    return v / (1.0f + __expf(-v));
}

__global__ void cvt_f32_to_bf16(const float* __restrict__ in,
                                unsigned short* __restrict__ out, int n4) {
    int i = blockIdx.x * blockDim.x + threadIdx.x;
    if (i >= n4) return;
    float4 v = reinterpret_cast<const float4*>(in)[i];
    ushort4 o;
    o.x = f2bf(v.x); o.y = f2bf(v.y); o.z = f2bf(v.z); o.w = f2bf(v.w);
    reinterpret_cast<ushort4*>(out)[i] = o;
}

// FOLDED LDS tile: 256 rows x 32 bf16 stored as [128 phys rows][128 B]:
// cols 0-63B hold rows 0-127, cols 64-127B hold rows 128-255. Logical slot
// s = (fold<<2)|(kb>>4); phys slot p = s ^ (r&7) (XOR swizzle, R9-verified
// class: 16-consecutive-row fragment reads -> 8 slots x2 = 2-way, free).
__device__ __forceinline__ bf16x8 lds_frag(const unsigned short* buf, int r, int kb) {
    int s = ((r >> 7) << 2) | (kb >> 4);
    int p = s ^ (r & 7);
    int lin = (r & 127) * 128 + (p << 4);
    return *reinterpret_cast<const bf16x8*>(reinterpret_cast<const char*>(buf) + lin);
}

#define BARRIER()    __builtin_amdgcn_s_barrier()
#define WAIT_VM(N)   asm volatile("s_waitcnt vmcnt(" #N ")" ::: "memory")

// Stage one 8KB half (64 phys rows = global rows {c*64..}+{128+c*64..}) of a
// K32-tile into LDS. Dest = wave-uniform base + lane*16 (linear); the fold +
// XOR swizzle (and B's band row-permutation) are applied by inverse-permuting
// the per-lane GLOBAL source offset (rule #21).
#define STAGE32(basePtr, soffX, ko, dstUshort, c) \
    __builtin_amdgcn_global_load_lds( \
        (const __attribute__((address_space(1))) void*)((basePtr) + (soffX) + (size_t)(c) * 64 * K + (ko)), \
        (__attribute__((address_space(3))) void*)(reinterpret_cast<char*>(dstUshort) + ((c) << 13) + (wave << 10)), \
        16, 0, 0)

// B read: frag nf rows wc*64 + nf*16 + ln15; due to staging row-permutation,
// frag nf lane p holds global col 4p+nf of the wave's 64-col band.
#define READ_B4(tB) \
    _Pragma("unroll") for (int nf = 0; nf < 4; ++nf) \
        bfrag[nf] = lds_frag(tB, wc*64 + nf*16 + ln15, kb16)

#define READ_A4(AF, tA, b) \
    _Pragma("unroll") for (int i = 0; i < 4; ++i) \
        AF[i] = lds_frag(tA, wr*128 + ((b)*4 + i)*16 + ln15, kb16)

// 16 MFMA: one A-batch (4 mf) x 4 nf, K=32.
#define MG16(b, AF) \
    _Pragma("unroll") for (int mi = 0; mi < 4; ++mi) \
    _Pragma("unroll") for (int nf = 0; nf < 4; ++nf) \
        acc[(b)*4 + mi][nf] = __builtin_amdgcn_mfma_f32_16x16x32_bf16( \
            AF[mi], bfrag[nf], acc[(b)*4 + mi][nf], 0, 0, 0)

// One K32-tile, single region, 1 barrier, 1 counted vmcnt.
// Slot math: tile j reads slot j%3, stages tile j+2 into slot (j+2)%3
// (= slot of tile j-1, fully consumed before the barrier ending tile j-1).
// Gate: outstanding = tiles j+1 (4) + j+2 (4); VM(4) retires tile j+1,
// whose loads were issued during tile j-1 (~1.3 tiles of latency cover).
#define KTILE3(sR, sW, jj, SG, VMN) do { \
    const unsigned short* tA = smem + (sR) * 8192; \
    const unsigned short* tB = smem + 24576 + (sR) * 8192; \
    unsigned short* dA = smem + (sW) * 8192; \
    unsigned short* dB = smem + 24576 + (sW) * 8192; \
    READ_B4(tB); \
    if (SG) { const int ko = ((jj) + 2) << 5; \
        STAGE32(baseB, soffB, ko, dB, 0); STAGE32(baseB, soffB, ko, dB, 1); } \
    READ_A4(af0, tA, 0); \
    if (SG) { const int ko = ((jj) + 2) << 5; \
        STAGE32(baseA, soffA, ko, dA, 0); STAGE32(baseA, soffA, ko, dA, 1); } \
    READ_A4(af1, tA, 1); \
    __builtin_amdgcn_s_setprio(1); MG16(0, af0); __builtin_amdgcn_s_setprio(0); \
    __builtin_amdgcn_s_setprio(1); MG16(1, af1); __builtin_amdgcn_s_setprio(0); \
    WAIT_VM(VMN); \
    BARRIER(); \
} while (0)

// NT GEMM, 256^2 triple-buffered K32: C = A[M,K] * Bm[N,K]^T, bf16, fp32 acc.
// EPI=0: Hout = bf16(silu(C)) (ushort4 stores);
// EPI=1: fused bias + dynamic causal conv + silu, shfl-free lane-local w-sum.
template <int EPI>
__global__ __launch_bounds__(512, 2)
void gemm8p(const unsigned short* __restrict__ A,
            const unsigned short* __restrict__ Bm,
            int M, int N, int K,
            unsigned short* __restrict__ Hout,
            const float* __restrict__ bias,
            const float* __restrict__ Xf,
            float* __restrict__ Out) {
    __shared__ __align__(16) unsigned short smem[49152];  // 96 KB

    const int tid  = threadIdx.x;
    const int wave = tid >> 6, lane = tid & 63;
    const int wr = wave >> 2, wc = wave & 3;        // 2M x 4N wave grid
    const int ln15 = lane & 15;
    const int kb16 = (lane >> 4) * 16;              // 16B k-slot (K=32 row)

    // Region-supertile XCD swizzle (bijective; needs GX%4==0, GY%2==0)
    const int GX = gridDim.x, GY = gridDim.y;
    const int bid = blockIdx.y * GX + blockIdx.x;
    const int xcd = bid & 7;
    const int idx = bid >> 3;
    const int W_ = GX >> 2;
    const int rr = idx / W_, cc = idx % W_;
    const int by = (xcd >> 2) * (GY >> 1) + rr;
    const int bx = (xcd & 3) * W_ + cc;
    const int m0 = by * BM, n0 = bx * BN;

    const int nk = K >> 5;   // K-tiles of 32 (=64 here; assumes nk%3==1)

    // Per-lane staging source (inverse of the folded+swizzled layout):
    // phys fold-row frl = wave*8 + (lane>>3), phys slot lane&7;
    // logical slot s = (lane&7)^(lane>>3); fold = s>>2; k-off = (s&3)*8.
    const int frl  = (wave << 3) + (lane >> 3);
    const int sl   = (lane & 7) ^ (lane >> 3);
    const int kbu  = (sl & 3) << 3;                 // ushort units
    const int gA0  = frl + 128 * (sl >> 2);         // global tile row, call 0
    const size_t soffA = (size_t)gA0 * K + kbu;
    // B: band-local row permutation pi(rho) = ((rho&15)<<2)|(rho>>4)
    const int rho  = gA0 & 63;
    const int prho = ((rho & 15) << 2) | (rho >> 4);
    const size_t soffB = (size_t)(((gA0 >> 6) << 6) + prho) * K + kbu;
    const unsigned short* baseA = A + (size_t)m0 * K;
    const unsigned short* baseB = Bm + (size_t)n0 * K;

    f32x4 acc[8][4];
#pragma unroll
    for (int i = 0; i < 8; ++i)
#pragma unroll
        for (int j = 0; j < 4; ++j) acc[i][j] = (f32x4)0.0f;

    bf16x8 bfrag[4], af0[4], af1[4];

    // ---- prologue: stage tiles 0 (slot0) and 1 (slot1); gate tile 0 ----
    {
        unsigned short* a0 = smem;               unsigned short* b0 = smem + 24576;
        unsigned short* a1 = smem + 8192;        unsigned short* b1 = smem + 32768;
        STAGE32(baseB, soffB, 0, b0, 0);  STAGE32(baseB, soffB, 0, b0, 1);
        STAGE32(baseA, soffA, 0, a0, 0);  STAGE32(baseA, soffA, 0, a0, 1);
        STAGE32(baseB, soffB, 32, b1, 0); STAGE32(baseB, soffB, 32, b1, 1);
        STAGE32(baseA, soffA, 32, a1, 0); STAGE32(baseA, soffA, 32, a1, 1);
    }
    WAIT_VM(4);   // tile 0 landed; tile 1 in flight
    BARRIER();

    // ---- main loop: 3 tiles/iter; tiles nk-4..nk-1 peeled ----
    for (int it = 0; it < (nk - 4) / 3; ++it) {
        const int j = it * 3;
        KTILE3(0, 2, j,     1, 4);
        KTILE3(1, 0, j + 1, 1, 4);
        KTILE3(2, 1, j + 2, 1, 4);
    }
    KTILE3(0, 2, nk - 4, 1, 4);   // stages nk-2
    KTILE3(1, 0, nk - 3, 1, 4);   // stages nk-1
    KTILE3(2, 1, nk - 2, 0, 0);   // drain
    KTILE3(0, 2, nk - 1, 0, 0);

    // ---- epilogue ----
    // Lane p (=ln15) holds, across nf=0..3, output cols wc*64 + p*4 + nf.
    if (EPI == 0) {
        const size_t colbase = n0 + wc * 64 + ln15 * 4;
#pragma unroll
        for (int mf = 0; mf < 8; ++mf) {
            int rowb = m0 + wr * 128 + mf * 16 + (lane >> 4) * 4;
#pragma unroll
            for (int r2 = 0; r2 < 4; ++r2) {
                ushort4 h4;
                h4.x = f2bf(silu_f(acc[mf][0][r2]));
                h4.y = f2bf(silu_f(acc[mf][1][r2]));
                h4.z = f2bf(silu_f(acc[mf][2][r2]));
                h4.w = f2bf(silu_f(acc[mf][3][r2]));
                *reinterpret_cast<ushort4*>(&Hout[(size_t)(rowb + r2) * N + colbase]) = h4;
            }
        }
    } else {
        // Stage x-window into LDS: rows ts = t0-3 .. t0+255 (259), 64 d cols.
        const int t0 = m0 & (T_DIM - 1);
        const int bidx = m0 >> 12;
        const int dbase = n0 >> 2;
        float* Xw = reinterpret_cast<float*>(smem);   // [259][XW_STRIDE] = 70KB
        for (int idx2 = tid; idx2 < 259 * 16; idx2 += 512) {
            int rw = idx2 >> 4, q = (idx2 & 15) << 2;
            int ts = t0 - 3 + rw;
            float4 v = make_float4(0.f, 0.f, 0.f, 0.f);
            if (ts >= 0)
                v = *reinterpret_cast<const float4*>(
                    &Xf[((size_t)bidx * T_DIM + ts) * D_DIM + dbase + q]);
            float* p = &Xw[rw * XW_STRIDE + q];
            p[0] = v.x; p[1] = v.y; p[2] = v.z; p[3] = v.w;
        }
        __syncthreads();

        // out[b,t,d] = silu(sum_w x[b,t-3+w,d] * (C+bias)[t, d*4+w]);
        // lane-local: d = dbase + wc*16 + p, w = nf. No shfl.
        const int dloc = wc * 16 + ln15;
        const float4 bias4 = *reinterpret_cast<const float4*>(
            &bias[n0 + wc * 64 + ln15 * 4]);
#pragma unroll
        for (int mf = 0; mf < 8; ++mf) {
            int lrow0 = wr * 128 + mf * 16 + (lane >> 4) * 4;
            float xr[7];
#pragma unroll
            for (int q = 0; q < 7; ++q)
                xr[q] = Xw[(lrow0 + q) * XW_STRIDE + dloc];
#pragma unroll
            for (int r2 = 0; r2 < 4; ++r2) {
                float v = (acc[mf][0][r2] + bias4.x) * xr[r2 + 0];
                v      += (acc[mf][1][r2] + bias4.y) * xr[r2 + 1];
                v      += (acc[mf][2][r2] + bias4.z) * xr[r2 + 2];
                v      += (acc[mf][3][r2] + bias4.w) * xr[r2 + 3];
                int lrow = lrow0 + r2;
                Out[((size_t)bidx * T_DIM + (t0 + lrow)) * D_DIM + dbase + dloc] = silu_f(v);
            }
        }
    }
}

extern "C" void kernel_launch(void* const* d_in, const int* in_sizes, int n_in,
                              void* d_out, int out_size, void* d_ws, size_t ws_size,
                              hipStream_t stream) {
    const float* x    = (const float*)d_in[0];  // [B,T,D]
    const float* w1   = (const float*)d_in[1];  // [H,D]
    const float* w2w  = (const float*)d_in[2];  // [D*W,H]
    const float* w2b  = (const float*)d_in[3];  // [D*W]
    float* out = (float*)d_out;

    // Workspace: ws0 = xb [M,D] bf16 (later reused for w2wb [N2,H] bf16),
    //            ws1 = w1b [H,D] bf16, ws2 = hb [M,H] bf16.
    unsigned short* ws0 = (unsigned short*)d_ws;
    unsigned short* ws1 = ws0 + (size_t)M_DIM * D_DIM;
    unsigned short* ws2 = ws1 + (size_t)H_DIM * D_DIM;

    const int CT = 256;
    {
        int n4 = (M_DIM * D_DIM) / 4;
        cvt_f32_to_bf16<<<(n4 + CT - 1) / CT, CT, 0, stream>>>(x, ws0, n4);
    }
    {
        int n4 = (H_DIM * D_DIM) / 4;
        cvt_f32_to_bf16<<<(n4 + CT - 1) / CT, CT, 0, stream>>>(w1, ws1, n4);
    }
    // GEMM1: hb = silu(xb @ w1b^T)  [8192, 2048]
    gemm8p<0><<<dim3(H_DIM / BN, M_DIM / BM), 512, 0, stream>>>(
        ws0, ws1, M_DIM, H_DIM, D_DIM, ws2, nullptr, nullptr, nullptr);
    // convert w2_w into ws0 (xb now dead)
    {
        int n4 = (N2_DIM * H_DIM) / 4;
        cvt_f32_to_bf16<<<(n4 + CT - 1) / CT, CT, 0, stream>>>(w2w, ws0, n4);
    }
    // GEMM2 + fused bias/conv/silu -> out
    gemm8p<1><<<dim3(N2_DIM / BN, M_DIM / BM), 512, 0, stream>>>(
        ws2, ws0, M_DIM, N2_DIM, H_DIM, nullptr, w2b, x, out);
}

// Round 12
// 332.674 us; speedup vs baseline: 1.0552x; 1.0552x over previous
//
#include <hip/hip_runtime.h>
#include <hip/hip_bf16.h>
#include <math.h>

// Problem constants (B=2, T=4096, D=2048, H=2048, W=4)
#define B_DIM 2
#define T_DIM 4096
#define D_DIM 2048
#define H_DIM 2048
#define W_K   4
#define M_DIM (B_DIM * T_DIM)   // 8192 tokens
#define N2_DIM (D_DIM * W_K)    // 8192

typedef __bf16 bf16x8 __attribute__((ext_vector_type(8)));
typedef float  f32x4  __attribute__((ext_vector_type(4)));

// 256x256 tile, K-tile 64, double-buffered, 8 waves (2M x 4N).
// 2 barriers per K-tile; compiler-scheduled ds_read/MFMA overlap.
// mg3's MFMA is DEFERRED across the tile-end barrier (register pipeline):
// it executes at the start of the next tile's region 1, filling the
// read-head stall where all waves previously idled on lgkm.
#define BM 256
#define BN 256
#define BKT 64
#define XW_STRIDE 68   // f32 stride for epilogue x-window

__device__ __forceinline__ unsigned short f2bf(float f) {
    unsigned int u = __float_as_uint(f);
    unsigned int r = (u + 0x7FFFu + ((u >> 16) & 1u)) >> 16;  // RNE
    return (unsigned short)r;
}

__device__ __forceinline__ float silu_f(float v) {
    return v / (1.0f + __expf(-v));
}

__global__ void cvt_f32_to_bf16(const float* __restrict__ in,
                                unsigned short* __restrict__ out, int n4) {
    int i = blockIdx.x * blockDim.x + threadIdx.x;
    if (i >= n4) return;
    float4 v = reinterpret_cast<const float4*>(in)[i];
    ushort4 o;
    o.x = f2bf(v.x); o.y = f2bf(v.y); o.z = f2bf(v.z); o.w = f2bf(v.w);
    reinterpret_cast<ushort4*>(out)[i] = o;
}

// LDS tile: [256 rows][64 bf16] = 128 B/row, XOR swizzle (R9-verified, 0 conflicts):
//   phys = r*128 + (kb ^ ((r&7)<<4))
__device__ __forceinline__ bf16x8 lds_frag(const unsigned short* buf, int r, int kb) {
    int lin = r * 128 + (kb ^ ((r & 7) << 4));
    return *reinterpret_cast<const bf16x8*>(reinterpret_cast<const char*>(buf) + lin);
}

#define BARRIER()    __builtin_amdgcn_s_barrier()
#define WAIT_VM(N)   asm volatile("s_waitcnt vmcnt(" #N ")" ::: "memory")

// Stage one 8KB chunk (64 rows x 64 cols bf16) of a K-tile into LDS.
// Dest = wave-uniform base + lane*16 (linear); swizzle applied by inverse-
// permuting the per-lane GLOBAL source (rule #21); for B additionally the
// within-band ROW permutation pi(r) = ((r&15)<<2)|(r>>4).
#define STAGE64(basePtr, soffX, ko, dstUshort, chunk) \
    __builtin_amdgcn_global_load_lds( \
        (const __attribute__((address_space(1))) void*)((basePtr) + (soffX) + (size_t)(chunk) * 64 * K + (ko)), \
        (__attribute__((address_space(3))) void*)(reinterpret_cast<char*>(dstUshort) + ((chunk) << 13) + (wave << 10)), \
        16, 0, 0)

// 16 MFMA for one M-group: 2 Mfrags x 4 Nfrags x 2 K-steps.
#define MG_MFMA(mg, AF) \
    _Pragma("unroll") for (int kk = 0; kk < 2; ++kk) \
    _Pragma("unroll") for (int mrel = 0; mrel < 2; ++mrel) \
    _Pragma("unroll") for (int nf = 0; nf < 4; ++nf) \
        acc[(mg)*2 + mrel][nf] = __builtin_amdgcn_mfma_f32_16x16x32_bf16( \
            AF[mrel][kk], bfrag[nf][kk], acc[(mg)*2 + mrel][nf], 0, 0, 0)

// B read: consecutive rows (conflict-free); staging row-permutation makes
// fragment nf lane p hold global col 4p+nf of the wave's 64-col band.
#define READ_B(tB) \
    _Pragma("unroll") for (int nf = 0; nf < 4; ++nf) \
    _Pragma("unroll") for (int kk = 0; kk < 2; ++kk) \
        bfrag[nf][kk] = lds_frag(tB, wc*64 + nf*16 + ln15, kk*64 + kb16)

#define READ_A(AF, tA, mg) \
    _Pragma("unroll") for (int mrel = 0; mrel < 2; ++mrel) \
    _Pragma("unroll") for (int kk = 0; kk < 2; ++kk) \
        AF[mrel][kk] = lds_frag(tA, wr*128 + (mg)*32 + mrel*16 + ln15, kk*64 + kb16)

// One K-tile, 2 barriers, mg3 deferred across BAR2 (hazard audit in header).
// PREV=1: execute previous tile's mg3 (af1+bfrag registers) first — the
// following B/A reads overwrite those registers (WAR => reads issue after
// MFMA issue => MFMA pipe overlaps the read burst).
// vmcnt ledger identical to R9: issue order A2,B1,A1,B2; steady outstanding
// 14 at gate; VM(6) retires tile j+1, leaves {B1,A1,B2}(j+2).
#define KTILE_D(bi, jj, PREV, SA2, SB, VMN) do { \
    const unsigned short* tA = smem + (bi) * 16384; \
    const unsigned short* tB = smem + 32768 + (bi) * 16384; \
    unsigned short* oA = smem + ((bi) ^ 1) * 16384; \
    unsigned short* cA = smem + (bi) * 16384; \
    unsigned short* cB = smem + 32768 + (bi) * 16384; \
    if (PREV) { __builtin_amdgcn_s_setprio(1); MG_MFMA(3, af1); __builtin_amdgcn_s_setprio(0); } \
    READ_B(tB); \
    READ_A(af0, tA, 0); \
    if (SA2) { const int ko = ((jj) + 1) << 6; \
        STAGE64(baseA, soffA, ko, oA, 1); STAGE64(baseA, soffA, ko, oA, 3); } \
    READ_A(af1, tA, 1); \
    __builtin_amdgcn_s_setprio(1); MG_MFMA(0, af0); __builtin_amdgcn_s_setprio(0); \
    __builtin_amdgcn_s_setprio(1); MG_MFMA(1, af1); __builtin_amdgcn_s_setprio(0); \
    BARRIER(); \
    READ_A(af0, tA, 2); \
    if (SB) { const int ko = ((jj) + 2) << 6; \
        STAGE64(baseB, soffB, ko, cB, 0); STAGE64(baseB, soffB, ko, cB, 1); \
        STAGE64(baseA, soffA, ko, cA, 0); STAGE64(baseA, soffA, ko, cA, 2); } \
    READ_A(af1, tA, 3); \
    __builtin_amdgcn_s_setprio(1); MG_MFMA(2, af0); __builtin_amdgcn_s_setprio(0); \
    if (SB) { const int ko = ((jj) + 2) << 6; \
        STAGE64(baseB, soffB, ko, cB, 2); STAGE64(baseB, soffB, ko, cB, 3); } \
    /* mg3 NOT executed here: af1 + bfrag stay live across BAR2 */ \
    WAIT_VM(VMN); \
    BARRIER(); \
} while (0)

// NT GEMM, 256^2 dbuf, 2-barrier K-tile + deferred-mg3 register pipeline.
// EPI=0: Hout = bf16(silu(C)) (ushort4-packed stores);
// EPI=1: fused bias + dynamic causal conv + silu, shfl-free lane-local w-sum.
template <int EPI>
__global__ __launch_bounds__(512, 2)
void gemm8p(const unsigned short* __restrict__ A,
            const unsigned short* __restrict__ Bm,
            int M, int N, int K,
            unsigned short* __restrict__ Hout,
            const float* __restrict__ bias,
            const float* __restrict__ Xf,
            float* __restrict__ Out) {
    __shared__ __align__(16) unsigned short smem[65536];  // 128 KB

    const int tid  = threadIdx.x;
    const int wave = tid >> 6, lane = tid & 63;
    const int wr = wave >> 2, wc = wave & 3;        // 2M x 4N wave grid
    const int ln15 = lane & 15;
    const int kb16 = (lane >> 4) * 16;              // 16B k-slot within 128B row

    // Region-supertile XCD swizzle (bijective; needs GX%4==0, GY%2==0)
    const int GX = gridDim.x, GY = gridDim.y;
    const int bid = blockIdx.y * GX + blockIdx.x;
    const int xcd = bid & 7;
    const int idx = bid >> 3;
    const int W_ = GX >> 2;
    const int rr = idx / W_, cc = idx % W_;
    const int by = (xcd >> 2) * (GY >> 1) + rr;
    const int bx = (xcd & 3) * W_ + cc;
    const int m0 = by * BM, n0 = bx * BN;

    const int nk = K >> 6;   // K-tiles of 64 (=32 here)

    // Per-thread staging offsets (R9): phys row srow = wave*8 + lane/8,
    // phys slot lane&7; logical col slot = (lane&7) ^ (lane>>3)  [s2(r)=r&7].
    const int srow = (wave << 3) + (lane >> 3);
    const int scol = (((lane & 7) ^ (lane >> 3)) << 3);  // ushort units
    const size_t soffA = (size_t)srow * K + scol;
    const int prow = ((srow & 15) << 2) | (srow >> 4);   // pi(srow) for B
    const size_t soffB = (size_t)prow * K + scol;
    const unsigned short* baseA = A + (size_t)m0 * K;
    const unsigned short* baseB = Bm + (size_t)n0 * K;

    f32x4 acc[8][4];
#pragma unroll
    for (int i = 0; i < 8; ++i)
#pragma unroll
        for (int j = 0; j < 4; ++j) acc[i][j] = (f32x4)0.0f;

    bf16x8 bfrag[4][2], af0[2][2], af1[2][2];

    // ---- prologue: tile 0 all 4 halves + tile 1's B1,A1,B2 (A2(1) in tile0) ----
    {
        unsigned short* dA0 = smem;
        unsigned short* dB0 = smem + 32768;
        unsigned short* dA1 = smem + 16384;
        unsigned short* dB1 = smem + 49152;
        STAGE64(baseB, soffB, 0, dB0, 0); STAGE64(baseB, soffB, 0, dB0, 1);
        STAGE64(baseB, soffB, 0, dB0, 2); STAGE64(baseB, soffB, 0, dB0, 3);
        STAGE64(baseA, soffA, 0, dA0, 0); STAGE64(baseA, soffA, 0, dA0, 1);
        STAGE64(baseA, soffA, 0, dA0, 2); STAGE64(baseA, soffA, 0, dA0, 3);
        STAGE64(baseB, soffB, BKT, dB1, 0); STAGE64(baseB, soffB, BKT, dB1, 1);  // B1(1)
        STAGE64(baseA, soffA, BKT, dA1, 0); STAGE64(baseA, soffA, BKT, dA1, 2);  // A1(1)
        STAGE64(baseB, soffB, BKT, dB1, 2); STAGE64(baseB, soffB, BKT, dB1, 3);  // B2(1)
    }
    WAIT_VM(6);   // tile 0 landed; tile 1's 3 halves in flight
    BARRIER();

    // ---- main loop: tile 0 peeled (no deferred work); tail tiles peeled ----
    KTILE_D(0, 0, 0, 1, 1, 6);
    KTILE_D(1, 1, 1, 1, 1, 6);
    for (int it = 1; it < (nk >> 1) - 1; ++it) {
        const int j = it << 1;
        KTILE_D(0, j,     1, 1, 1, 6);
        KTILE_D(1, j + 1, 1, 1, 1, 6);
    }
    KTILE_D(0, nk - 2, 1, 1, 0, 0);   // stage only A2(nk-1); drain
    KTILE_D(1, nk - 1, 1, 0, 0, 0);
    // final deferred mg3 of tile nk-1
    __builtin_amdgcn_s_setprio(1); MG_MFMA(3, af1); __builtin_amdgcn_s_setprio(0);

    // ---- epilogue ----
    // Lane p (=ln15) holds, across nf=0..3, output cols wc*64 + p*4 + nf.
    if (EPI == 0) {
        const size_t colbase = n0 + wc * 64 + ln15 * 4;
#pragma unroll
        for (int mf = 0; mf < 8; ++mf) {
            int rowb = m0 + wr * 128 + mf * 16 + (lane >> 4) * 4;
#pragma unroll
            for (int r2 = 0; r2 < 4; ++r2) {
                ushort4 h4;
                h4.x = f2bf(silu_f(acc[mf][0][r2]));
                h4.y = f2bf(silu_f(acc[mf][1][r2]));
                h4.z = f2bf(silu_f(acc[mf][2][r2]));
                h4.w = f2bf(silu_f(acc[mf][3][r2]));
                *reinterpret_cast<ushort4*>(&Hout[(size_t)(rowb + r2) * N + colbase]) = h4;
            }
        }
    } else {
        // Stage x-window into LDS: rows ts = t0-3 .. t0+255 (259), 64 d cols.
        const int t0 = m0 & (T_DIM - 1);
        const int bidx = m0 >> 12;
        const int dbase = n0 >> 2;
        float* Xw = reinterpret_cast<float*>(smem);   // [259][XW_STRIDE]
        __syncthreads();   // all LDS reads of the K-loop are pre-BAR2; safe
        for (int idx2 = tid; idx2 < 259 * 16; idx2 += 512) {
            int rw = idx2 >> 4, q = (idx2 & 15) << 2;
            int ts = t0 - 3 + rw;
            float4 v = make_float4(0.f, 0.f, 0.f, 0.f);
            if (ts >= 0)
                v = *reinterpret_cast<const float4*>(
                    &Xf[((size_t)bidx * T_DIM + ts) * D_DIM + dbase + q]);
            float* p = &Xw[rw * XW_STRIDE + q];
            p[0] = v.x; p[1] = v.y; p[2] = v.z; p[3] = v.w;
        }
        __syncthreads();

        // out[b,t,d] = silu(sum_w x[b,t-3+w,d] * (C+bias)[t, d*4+w]);
        // lane-local: d = dbase + wc*16 + p, w = nf. No shfl.
        const int dloc = wc * 16 + ln15;
        const float4 bias4 = *reinterpret_cast<const float4*>(
            &bias[n0 + wc * 64 + ln15 * 4]);
#pragma unroll
        for (int mf = 0; mf < 8; ++mf) {
            int lrow0 = wr * 128 + mf * 16 + (lane >> 4) * 4;
            float xr[7];
#pragma unroll
            for (int q = 0; q < 7; ++q)
                xr[q] = Xw[(lrow0 + q) * XW_STRIDE + dloc];
#pragma unroll
            for (int r2 = 0; r2 < 4; ++r2) {
                float v = (acc[mf][0][r2] + bias4.x) * xr[r2 + 0];
                v      += (acc[mf][1][r2] + bias4.y) * xr[r2 + 1];
                v      += (acc[mf][2][r2] + bias4.z) * xr[r2 + 2];
                v      += (acc[mf][3][r2] + bias4.w) * xr[r2 + 3];
                int lrow = lrow0 + r2;
                Out[((size_t)bidx * T_DIM + (t0 + lrow)) * D_DIM + dbase + dloc] = silu_f(v);
            }
        }
    }
}

extern "C" void kernel_launch(void* const* d_in, const int* in_sizes, int n_in,
                              void* d_out, int out_size, void* d_ws, size_t ws_size,
                              hipStream_t stream) {
    const float* x    = (const float*)d_in[0];  // [B,T,D]
    const float* w1   = (const float*)d_in[1];  // [H,D]
    const float* w2w  = (const float*)d_in[2];  // [D*W,H]
    const float* w2b  = (const float*)d_in[3];  // [D*W]
    float* out = (float*)d_out;

    // Workspace: ws0 = xb [M,D] bf16 (later reused for w2wb [N2,H] bf16),
    //            ws1 = w1b [H,D] bf16, ws2 = hb [M,H] bf16.
    unsigned short* ws0 = (unsigned short*)d_ws;
    unsigned short* ws1 = ws0 + (size_t)M_DIM * D_DIM;
    unsigned short* ws2 = ws1 + (size_t)H_DIM * D_DIM;

    const int CT = 256;
    {
        int n4 = (M_DIM * D_DIM) / 4;
        cvt_f32_to_bf16<<<(n4 + CT - 1) / CT, CT, 0, stream>>>(x, ws0, n4);
    }
    {
        int n4 = (H_DIM * D_DIM) / 4;
        cvt_f32_to_bf16<<<(n4 + CT - 1) / CT, CT, 0, stream>>>(w1, ws1, n4);
    }
    // GEMM1: hb = silu(xb @ w1b^T)  [8192, 2048]
    gemm8p<0><<<dim3(H_DIM / BN, M_DIM / BM), 512, 0, stream>>>(
        ws0, ws1, M_DIM, H_DIM, D_DIM, ws2, nullptr, nullptr, nullptr);
    // convert w2_w into ws0 (xb now dead)
    {
        int n4 = (N2_DIM * H_DIM) / 4;
        cvt_f32_to_bf16<<<(n4 + CT - 1) / CT, CT, 0, stream>>>(w2w, ws0, n4);
    }
    // GEMM2 + fused bias/conv/silu -> out
    gemm8p<1><<<dim3(N2_DIM / BN, M_DIM / BM), 512, 0, stream>>>(
        ws2, ws0, M_DIM, N2_DIM, H_DIM, nullptr, w2b, x, out);
}

// Round 13
// 324.879 us; speedup vs baseline: 1.0806x; 1.0240x over previous
//
#include <hip/hip_runtime.h>
#include <hip/hip_bf16.h>
#include <math.h>

// Problem constants (B=2, T=4096, D=2048, H=2048, W=4)
#define B_DIM 2
#define T_DIM 4096
#define D_DIM 2048
#define H_DIM 2048
#define W_K   4
#define M_DIM (B_DIM * T_DIM)   // 8192 tokens
#define N2_DIM (D_DIM * W_K)    // 8192

typedef __bf16 bf16x8 __attribute__((ext_vector_type(8)));
typedef float  f32x4  __attribute__((ext_vector_type(4)));

// 256x256 tile, K-tile 64, double-buffered, 8 waves (2M x 4N).
// 2 barriers per K-tile; SYMMETRIC deferred-MFMA register pipeline:
//   mg1 deferred across BAR1 (executes at region-2 head),
//   mg3 deferred across BAR2 (executes at next tile's region-1 head).
// Each barrier region = 16 register-fed MFMA (covering its read burst)
// + reads/stages + 16 LDS-fed MFMA.
#define BM 256
#define BN 256
#define BKT 64
#define XW_STRIDE 68   // f32 stride for epilogue x-window

__device__ __forceinline__ unsigned short f2bf(float f) {
    unsigned int u = __float_as_uint(f);
    unsigned int r = (u + 0x7FFFu + ((u >> 16) & 1u)) >> 16;  // RNE
    return (unsigned short)r;
}

__device__ __forceinline__ float silu_f(float v) {
    return v / (1.0f + __expf(-v));
}

__global__ void cvt_f32_to_bf16(const float* __restrict__ in,
                                unsigned short* __restrict__ out, int n4) {
    int i = blockIdx.x * blockDim.x + threadIdx.x;
    if (i >= n4) return;
    float4 v = reinterpret_cast<const float4*>(in)[i];
    ushort4 o;
    o.x = f2bf(v.x); o.y = f2bf(v.y); o.z = f2bf(v.z); o.w = f2bf(v.w);
    reinterpret_cast<ushort4*>(out)[i] = o;
}

// LDS tile: [256 rows][64 bf16] = 128 B/row, XOR swizzle (R9-verified, 0 conflicts):
//   phys = r*128 + (kb ^ ((r&7)<<4))
__device__ __forceinline__ bf16x8 lds_frag(const unsigned short* buf, int r, int kb) {
    int lin = r * 128 + (kb ^ ((r & 7) << 4));
    return *reinterpret_cast<const bf16x8*>(reinterpret_cast<const char*>(buf) + lin);
}

#define BARRIER()    __builtin_amdgcn_s_barrier()
#define WAIT_VM(N)   asm volatile("s_waitcnt vmcnt(" #N ")" ::: "memory")

// Stage one 8KB chunk (64 rows x 64 cols bf16) of a K-tile into LDS.
// Dest = wave-uniform base + lane*16 (linear); swizzle applied by inverse-
// permuting the per-lane GLOBAL source (rule #21); for B additionally the
// within-band ROW permutation pi(r) = ((r&15)<<2)|(r>>4).
#define STAGE64(basePtr, soffX, ko, dstUshort, chunk) \
    __builtin_amdgcn_global_load_lds( \
        (const __attribute__((address_space(1))) void*)((basePtr) + (soffX) + (size_t)(chunk) * 64 * K + (ko)), \
        (__attribute__((address_space(3))) void*)(reinterpret_cast<char*>(dstUshort) + ((chunk) << 13) + (wave << 10)), \
        16, 0, 0)

// 16 MFMA for one M-group: 2 Mfrags x 4 Nfrags x 2 K-steps.
#define MG_MFMA(mg, AF) \
    _Pragma("unroll") for (int kk = 0; kk < 2; ++kk) \
    _Pragma("unroll") for (int mrel = 0; mrel < 2; ++mrel) \
    _Pragma("unroll") for (int nf = 0; nf < 4; ++nf) \
        acc[(mg)*2 + mrel][nf] = __builtin_amdgcn_mfma_f32_16x16x32_bf16( \
            AF[mrel][kk], bfrag[nf][kk], acc[(mg)*2 + mrel][nf], 0, 0, 0)

// B read: consecutive rows (conflict-free); staging row-permutation makes
// fragment nf lane p hold global col 4p+nf of the wave's 64-col band.
#define READ_B(tB) \
    _Pragma("unroll") for (int nf = 0; nf < 4; ++nf) \
    _Pragma("unroll") for (int kk = 0; kk < 2; ++kk) \
        bfrag[nf][kk] = lds_frag(tB, wc*64 + nf*16 + ln15, kk*64 + kb16)

#define READ_A(AF, tA, mg) \
    _Pragma("unroll") for (int mrel = 0; mrel < 2; ++mrel) \
    _Pragma("unroll") for (int kk = 0; kk < 2; ++kk) \
        AF[mrel][kk] = lds_frag(tA, wr*128 + (mg)*32 + mrel*16 + ln15, kk*64 + kb16)

// One K-tile, 2 barriers, symmetric deferral (hazard audit in header).
// PREV=1: execute previous tile's mg3 (af1+bfrag registers) at region-1 head.
// mg1 always deferred across BAR1 into region-2 head (register-only there;
// its LDS reads completed pre-BAR1; A1(j+2) staging into chunks 0,2 occurs
// after BAR1, when mg0/mg1's LDS rows are dead).
// vmcnt ledger (= R9): issue order A2,B1,A1,B2; steady outstanding 14 at
// gate; VM(6) retires tile j+1, leaves {B1,A1,B2}(j+2).
#define KTILE_D(bi, jj, PREV, SA2, SB, VMN) do { \
    const unsigned short* tA = smem + (bi) * 16384; \
    const unsigned short* tB = smem + 32768 + (bi) * 16384; \
    unsigned short* oA = smem + ((bi) ^ 1) * 16384; \
    unsigned short* cA = smem + (bi) * 16384; \
    unsigned short* cB = smem + 32768 + (bi) * 16384; \
    if (PREV) { __builtin_amdgcn_s_setprio(1); MG_MFMA(3, af1); __builtin_amdgcn_s_setprio(0); } \
    READ_B(tB); \
    READ_A(af0, tA, 0); \
    if (SA2) { const int ko = ((jj) + 1) << 6; \
        STAGE64(baseA, soffA, ko, oA, 1); STAGE64(baseA, soffA, ko, oA, 3); } \
    READ_A(af1, tA, 1); \
    __builtin_amdgcn_s_setprio(1); MG_MFMA(0, af0); __builtin_amdgcn_s_setprio(0); \
    /* mg1 deferred: af1 + bfrag live across BAR1 */ \
    BARRIER(); \
    __builtin_amdgcn_s_setprio(1); MG_MFMA(1, af1); __builtin_amdgcn_s_setprio(0); \
    READ_A(af0, tA, 2); \
    if (SB) { const int ko = ((jj) + 2) << 6; \
        STAGE64(baseB, soffB, ko, cB, 0); STAGE64(baseB, soffB, ko, cB, 1); \
        STAGE64(baseA, soffA, ko, cA, 0); STAGE64(baseA, soffA, ko, cA, 2); } \
    READ_A(af1, tA, 3); \
    __builtin_amdgcn_s_setprio(1); MG_MFMA(2, af0); __builtin_amdgcn_s_setprio(0); \
    if (SB) { const int ko = ((jj) + 2) << 6; \
        STAGE64(baseB, soffB, ko, cB, 2); STAGE64(baseB, soffB, ko, cB, 3); } \
    /* mg3 deferred: af1 + bfrag live across BAR2 */ \
    WAIT_VM(VMN); \
    BARRIER(); \
} while (0)

// NT GEMM, 256^2 dbuf, 2-barrier K-tile + symmetric deferred-MFMA pipeline.
// EPI=0: Hout = bf16(silu(C)) (ushort4-packed stores);
// EPI=1: fused bias + dynamic causal conv + silu, shfl-free lane-local w-sum.
template <int EPI>
__global__ __launch_bounds__(512, 2)
void gemm8p(const unsigned short* __restrict__ A,
            const unsigned short* __restrict__ Bm,
            int M, int N, int K,
            unsigned short* __restrict__ Hout,
            const float* __restrict__ bias,
            const float* __restrict__ Xf,
            float* __restrict__ Out) {
    __shared__ __align__(16) unsigned short smem[65536];  // 128 KB

    const int tid  = threadIdx.x;
    const int wave = tid >> 6, lane = tid & 63;
    const int wr = wave >> 2, wc = wave & 3;        // 2M x 4N wave grid
    const int ln15 = lane & 15;
    const int kb16 = (lane >> 4) * 16;              // 16B k-slot within 128B row

    // Region-supertile XCD swizzle (bijective; needs GX%4==0, GY%2==0)
    const int GX = gridDim.x, GY = gridDim.y;
    const int bid = blockIdx.y * GX + blockIdx.x;
    const int xcd = bid & 7;
    const int idx = bid >> 3;
    const int W_ = GX >> 2;
    const int rr = idx / W_, cc = idx % W_;
    const int by = (xcd >> 2) * (GY >> 1) + rr;
    const int bx = (xcd & 3) * W_ + cc;
    const int m0 = by * BM, n0 = bx * BN;

    const int nk = K >> 6;   // K-tiles of 64 (=32 here)

    // Per-thread staging offsets (R9): phys row srow = wave*8 + lane/8,
    // phys slot lane&7; logical col slot = (lane&7) ^ (lane>>3)  [s2(r)=r&7].
    const int srow = (wave << 3) + (lane >> 3);
    const int scol = (((lane & 7) ^ (lane >> 3)) << 3);  // ushort units
    const size_t soffA = (size_t)srow * K + scol;
    const int prow = ((srow & 15) << 2) | (srow >> 4);   // pi(srow) for B
    const size_t soffB = (size_t)prow * K + scol;
    const unsigned short* baseA = A + (size_t)m0 * K;
    const unsigned short* baseB = Bm + (size_t)n0 * K;

    f32x4 acc[8][4];
#pragma unroll
    for (int i = 0; i < 8; ++i)
#pragma unroll
        for (int j = 0; j < 4; ++j) acc[i][j] = (f32x4)0.0f;

    bf16x8 bfrag[4][2], af0[2][2], af1[2][2];

    // ---- prologue: tile 0 all 4 halves + tile 1's B1,A1,B2 (A2(1) in tile0) ----
    {
        unsigned short* dA0 = smem;
        unsigned short* dB0 = smem + 32768;
        unsigned short* dA1 = smem + 16384;
        unsigned short* dB1 = smem + 49152;
        STAGE64(baseB, soffB, 0, dB0, 0); STAGE64(baseB, soffB, 0, dB0, 1);
        STAGE64(baseB, soffB, 0, dB0, 2); STAGE64(baseB, soffB, 0, dB0, 3);
        STAGE64(baseA, soffA, 0, dA0, 0); STAGE64(baseA, soffA, 0, dA0, 1);
        STAGE64(baseA, soffA, 0, dA0, 2); STAGE64(baseA, soffA, 0, dA0, 3);
        STAGE64(baseB, soffB, BKT, dB1, 0); STAGE64(baseB, soffB, BKT, dB1, 1);  // B1(1)
        STAGE64(baseA, soffA, BKT, dA1, 0); STAGE64(baseA, soffA, BKT, dA1, 2);  // A1(1)
        STAGE64(baseB, soffB, BKT, dB1, 2); STAGE64(baseB, soffB, BKT, dB1, 3);  // B2(1)
    }
    WAIT_VM(6);   // tile 0 landed; tile 1's 3 halves in flight
    BARRIER();

    // ---- main loop: tile 0 peeled (no prev mg3); tail tiles peeled ----
    KTILE_D(0, 0, 0, 1, 1, 6);
    KTILE_D(1, 1, 1, 1, 1, 6);
    for (int it = 1; it < (nk >> 1) - 1; ++it) {
        const int j = it << 1;
        KTILE_D(0, j,     1, 1, 1, 6);
        KTILE_D(1, j + 1, 1, 1, 1, 6);
    }
    KTILE_D(0, nk - 2, 1, 1, 0, 0);   // stage only A2(nk-1); drain
    KTILE_D(1, nk - 1, 1, 0, 0, 0);
    // final deferred mg3 of tile nk-1
    __builtin_amdgcn_s_setprio(1); MG_MFMA(3, af1); __builtin_amdgcn_s_setprio(0);

    // ---- epilogue ----
    // Lane p (=ln15) holds, across nf=0..3, output cols wc*64 + p*4 + nf.
    if (EPI == 0) {
        const size_t colbase = n0 + wc * 64 + ln15 * 4;
#pragma unroll
        for (int mf = 0; mf < 8; ++mf) {
            int rowb = m0 + wr * 128 + mf * 16 + (lane >> 4) * 4;
#pragma unroll
            for (int r2 = 0; r2 < 4; ++r2) {
                ushort4 h4;
                h4.x = f2bf(silu_f(acc[mf][0][r2]));
                h4.y = f2bf(silu_f(acc[mf][1][r2]));
                h4.z = f2bf(silu_f(acc[mf][2][r2]));
                h4.w = f2bf(silu_f(acc[mf][3][r2]));
                *reinterpret_cast<ushort4*>(&Hout[(size_t)(rowb + r2) * N + colbase]) = h4;
            }
        }
    } else {
        // Stage x-window into LDS: rows ts = t0-3 .. t0+255 (259), 64 d cols.
        const int t0 = m0 & (T_DIM - 1);
        const int bidx = m0 >> 12;
        const int dbase = n0 >> 2;
        float* Xw = reinterpret_cast<float*>(smem);   // [259][XW_STRIDE]
        __syncthreads();   // all K-loop LDS reads complete pre-BAR2; safe
        for (int idx2 = tid; idx2 < 259 * 16; idx2 += 512) {
            int rw = idx2 >> 4, q = (idx2 & 15) << 2;
            int ts = t0 - 3 + rw;
            float4 v = make_float4(0.f, 0.f, 0.f, 0.f);
            if (ts >= 0)
                v = *reinterpret_cast<const float4*>(
                    &Xf[((size_t)bidx * T_DIM + ts) * D_DIM + dbase + q]);
            float* p = &Xw[rw * XW_STRIDE + q];
            p[0] = v.x; p[1] = v.y; p[2] = v.z; p[3] = v.w;
        }
        __syncthreads();

        // out[b,t,d] = silu(sum_w x[b,t-3+w,d] * (C+bias)[t, d*4+w]);
        // lane-local: d = dbase + wc*16 + p, w = nf. No shfl.
        const int dloc = wc * 16 + ln15;
        const float4 bias4 = *reinterpret_cast<const float4*>(
            &bias[n0 + wc * 64 + ln15 * 4]);
#pragma unroll
        for (int mf = 0; mf < 8; ++mf) {
            int lrow0 = wr * 128 + mf * 16 + (lane >> 4) * 4;
            float xr[7];
#pragma unroll
            for (int q = 0; q < 7; ++q)
                xr[q] = Xw[(lrow0 + q) * XW_STRIDE + dloc];
#pragma unroll
            for (int r2 = 0; r2 < 4; ++r2) {
                float v = (acc[mf][0][r2] + bias4.x) * xr[r2 + 0];
                v      += (acc[mf][1][r2] + bias4.y) * xr[r2 + 1];
                v      += (acc[mf][2][r2] + bias4.z) * xr[r2 + 2];
                v      += (acc[mf][3][r2] + bias4.w) * xr[r2 + 3];
                int lrow = lrow0 + r2;
                Out[((size_t)bidx * T_DIM + (t0 + lrow)) * D_DIM + dbase + dloc] = silu_f(v);
            }
        }
    }
}

extern "C" void kernel_launch(void* const* d_in, const int* in_sizes, int n_in,
                              void* d_out, int out_size, void* d_ws, size_t ws_size,
                              hipStream_t stream) {
    const float* x    = (const float*)d_in[0];  // [B,T,D]
    const float* w1   = (const float*)d_in[1];  // [H,D]
    const float* w2w  = (const float*)d_in[2];  // [D*W,H]
    const float* w2b  = (const float*)d_in[3];  // [D*W]
    float* out = (float*)d_out;

    // Workspace: ws0 = xb [M,D] bf16 (later reused for w2wb [N2,H] bf16),
    //            ws1 = w1b [H,D] bf16, ws2 = hb [M,H] bf16.
    unsigned short* ws0 = (unsigned short*)d_ws;
    unsigned short* ws1 = ws0 + (size_t)M_DIM * D_DIM;
    unsigned short* ws2 = ws1 + (size_t)H_DIM * D_DIM;

    const int CT = 256;
    {
        int n4 = (M_DIM * D_DIM) / 4;
        cvt_f32_to_bf16<<<(n4 + CT - 1) / CT, CT, 0, stream>>>(x, ws0, n4);
    }
    {
        int n4 = (H_DIM * D_DIM) / 4;
        cvt_f32_to_bf16<<<(n4 + CT - 1) / CT, CT, 0, stream>>>(w1, ws1, n4);
    }
    // GEMM1: hb = silu(xb @ w1b^T)  [8192, 2048]
    gemm8p<0><<<dim3(H_DIM / BN, M_DIM / BM), 512, 0, stream>>>(
        ws0, ws1, M_DIM, H_DIM, D_DIM, ws2, nullptr, nullptr, nullptr);
    // convert w2_w into ws0 (xb now dead)
    {
        int n4 = (N2_DIM * H_DIM) / 4;
        cvt_f32_to_bf16<<<(n4 + CT - 1) / CT, CT, 0, stream>>>(w2w, ws0, n4);
    }
    // GEMM2 + fused bias/conv/silu -> out
    gemm8p<1><<<dim3(N2_DIM / BN, M_DIM / BM), 512, 0, stream>>>(
        ws2, ws0, M_DIM, N2_DIM, H_DIM, nullptr, w2b, x, out);
}